// Round 7
// baseline (733.041 us; speedup 1.0000x reference)
//
#include <hip/hip_runtime.h>
#include <hip/hip_bf16.h>

#define DD    768
#define NH    12
#define HDIM  64
#define LSEQ  1024
#define NB    4
#define SCALE 27.712812921102035f   // sqrt(768): reference DIVIDES by dim**-0.5

// ---------------------------------------------------------------------------
// Projection GEMM: C[M][768] = A[M][768] @ W[768][768]^T + bias.
// 128x128 tile, TK=16, 256 threads, 8x8 per thread.
// LDS is K-MAJOR (As_t[kk][m]) so each thread's fragment is a contiguous
// float4 -> ds_read_b128. Thread (tx,ty) owns rows {ty*4+i, 64+ty*4+i} and
// cols {tx*4+j, 64+tx*4+j}. Stride 132 floats: writes 2-way (free), reads
// broadcast/2-way (free).
// ---------------------------------------------------------------------------
__device__ __forceinline__ void gemm_128x128(const float* __restrict__ A,
                                             const float* __restrict__ W,
                                             const float* __restrict__ bias,
                                             float* __restrict__ C) {
    __shared__ __align__(16) float As_t[16][132];
    __shared__ __align__(16) float Ws_t[16][132];

    const int tid = threadIdx.x;
    const int tx  = tid & 15;   // col group: cols tx*4..tx*4+3 (+64)
    const int ty  = tid >> 4;   // row group: rows ty*4..ty*4+3 (+64)
    const int m0  = blockIdx.y * 128;
    const int n0  = blockIdx.x * 128;

    const int lr = tid >> 2;          // 0..63 staging row
    const int lc = (tid & 3) * 4;     // 0,4,8,12 staging k-offset

    float acc[8][8];
#pragma unroll
    for (int i = 0; i < 8; i++)
#pragma unroll
        for (int j = 0; j < 8; j++) acc[i][j] = 0.f;

    for (int k0 = 0; k0 < DD; k0 += 16) {
        // global loads issued before the barrier so they overlap prior compute
        float4 a0 = *(const float4*)&A[(size_t)(m0 + lr)      * DD + k0 + lc];
        float4 a1 = *(const float4*)&A[(size_t)(m0 + lr + 64) * DD + k0 + lc];
        float4 w0 = *(const float4*)&W[(size_t)(n0 + lr)      * DD + k0 + lc];
        float4 w1 = *(const float4*)&W[(size_t)(n0 + lr + 64) * DD + k0 + lc];
        __syncthreads();   // previous tile's compute reads done
#pragma unroll
        for (int c = 0; c < 4; c++) {
            As_t[lc + c][lr]      = (&a0.x)[c];
            As_t[lc + c][lr + 64] = (&a1.x)[c];
            Ws_t[lc + c][lr]      = (&w0.x)[c];
            Ws_t[lc + c][lr + 64] = (&w1.x)[c];
        }
        __syncthreads();
#pragma unroll
        for (int kk = 0; kk < 16; kk++) {
            float4 alo = *(const float4*)&As_t[kk][ty * 4];
            float4 ahi = *(const float4*)&As_t[kk][64 + ty * 4];
            float4 wlo = *(const float4*)&Ws_t[kk][tx * 4];
            float4 whi = *(const float4*)&Ws_t[kk][64 + tx * 4];
            float a[8] = {alo.x, alo.y, alo.z, alo.w, ahi.x, ahi.y, ahi.z, ahi.w};
            float w[8] = {wlo.x, wlo.y, wlo.z, wlo.w, whi.x, whi.y, whi.z, whi.w};
#pragma unroll
            for (int i = 0; i < 8; i++)
#pragma unroll
                for (int j = 0; j < 8; j++)
                    acc[i][j] = fmaf(a[i], w[j], acc[i][j]);
        }
    }

#pragma unroll
    for (int g = 0; g < 2; g++) {
        const int   colb = n0 + g * 64 + tx * 4;
        const float4 bv4 = *(const float4*)&bias[colb];
#pragma unroll
        for (int i = 0; i < 8; i++) {
            const int row = m0 + (i < 4 ? ty * 4 + i : 64 + ty * 4 + (i - 4));
            float4 o;
#pragma unroll
            for (int c = 0; c < 4; c++) (&o.x)[c] = acc[i][g * 4 + c] + (&bv4.x)[c];
            *(float4*)&C[(size_t)row * DD + colb] = o;
        }
    }
}

__global__ __launch_bounds__(256) void qkv_gemm(
        const float* __restrict__ A,
        const float* __restrict__ W0, const float* __restrict__ c0, float* __restrict__ O0,
        const float* __restrict__ W1, const float* __restrict__ c1, float* __restrict__ O1,
        const float* __restrict__ W2, const float* __restrict__ c2, float* __restrict__ O2) {
    const float* W; const float* bias; float* C;
    if      (blockIdx.z == 0) { W = W0; bias = c0; C = O0; }
    else if (blockIdx.z == 1) { W = W1; bias = c1; C = O1; }
    else                      { W = W2; bias = c2; C = O2; }
    gemm_128x128(A, W, bias, C);
}

__global__ __launch_bounds__(256) void proj_gemm(
        const float* __restrict__ A, const float* __restrict__ W,
        const float* __restrict__ bias, float* __restrict__ C) {
    gemm_128x128(A, W, bias, C);
}

// ---------------------------------------------------------------------------
// Logits GEMM: for bh = blockIdx.z, S[q][k] = <Q_bh[q,:], K_bh[k,:]>  (K=64).
// Raw logits written to the attn output region; softmax applies
// (s + qrel[bucket]) * SCALE. Same k-major/b128 structure as gemm_128x128.
// ---------------------------------------------------------------------------
__global__ __launch_bounds__(256) void logits_gemm(
        const float* __restrict__ Q, const float* __restrict__ K,
        float* __restrict__ Sout) {
    __shared__ __align__(16) float As_t[16][132];
    __shared__ __align__(16) float Ws_t[16][132];

    const int tid = threadIdx.x;
    const int tx  = tid & 15;
    const int ty  = tid >> 4;
    const int m0  = blockIdx.y * 128;          // q tile
    const int n0  = blockIdx.x * 128;          // k tile
    const int bh  = blockIdx.z;
    const int b   = bh / NH;
    const int h   = bh % NH;
    const size_t base = (size_t)b * LSEQ * DD + (size_t)h * HDIM;

    const int lr = tid >> 2;
    const int lc = (tid & 3) * 4;

    float acc[8][8];
#pragma unroll
    for (int i = 0; i < 8; i++)
#pragma unroll
        for (int j = 0; j < 8; j++) acc[i][j] = 0.f;

    for (int k0 = 0; k0 < HDIM; k0 += 16) {
        float4 a0 = *(const float4*)&Q[base + (size_t)(m0 + lr)      * DD + k0 + lc];
        float4 a1 = *(const float4*)&Q[base + (size_t)(m0 + lr + 64) * DD + k0 + lc];
        float4 w0 = *(const float4*)&K[base + (size_t)(n0 + lr)      * DD + k0 + lc];
        float4 w1 = *(const float4*)&K[base + (size_t)(n0 + lr + 64) * DD + k0 + lc];
        __syncthreads();
#pragma unroll
        for (int c = 0; c < 4; c++) {
            As_t[lc + c][lr]      = (&a0.x)[c];
            As_t[lc + c][lr + 64] = (&a1.x)[c];
            Ws_t[lc + c][lr]      = (&w0.x)[c];
            Ws_t[lc + c][lr + 64] = (&w1.x)[c];
        }
        __syncthreads();
#pragma unroll
        for (int kk = 0; kk < 16; kk++) {
            float4 alo = *(const float4*)&As_t[kk][ty * 4];
            float4 ahi = *(const float4*)&As_t[kk][64 + ty * 4];
            float4 wlo = *(const float4*)&Ws_t[kk][tx * 4];
            float4 whi = *(const float4*)&Ws_t[kk][64 + tx * 4];
            float a[8] = {alo.x, alo.y, alo.z, alo.w, ahi.x, ahi.y, ahi.z, ahi.w};
            float w[8] = {wlo.x, wlo.y, wlo.z, wlo.w, whi.x, whi.y, whi.z, whi.w};
#pragma unroll
            for (int i = 0; i < 8; i++)
#pragma unroll
                for (int j = 0; j < 8; j++)
                    acc[i][j] = fmaf(a[i], w[j], acc[i][j]);
        }
    }

    float* Sb = Sout + ((size_t)bh << 20);     // bh * 1024*1024
#pragma unroll
    for (int g = 0; g < 2; g++) {
        const int colb = n0 + g * 64 + tx * 4;
#pragma unroll
        for (int i = 0; i < 8; i++) {
            const int row = m0 + (i < 4 ? ty * 4 + i : 64 + ty * 4 + (i - 4));
            float4 o;
#pragma unroll
            for (int c = 0; c < 4; c++) (&o.x)[c] = acc[i][g * 4 + c];
            *(float4*)&Sb[(size_t)row * LSEQ + colb] = o;
        }
    }
}

// ---------------------------------------------------------------------------
// Row softmax (in place on the attn region). Block = 256 threads = 4 waves,
// one wave per row. Fuses: + qrel[bucket(k-q)], * SCALE, softmax, and emits
// the 5 rel_v bucket coefficients per row into `coef`. Memory-bound.
// ---------------------------------------------------------------------------
__global__ __launch_bounds__(256) void softmax_kernel(
        const float* __restrict__ Q, const float* __restrict__ rel_k,
        float* __restrict__ attn, float* __restrict__ coef) {
    __shared__ float relk[5][64];
    __shared__ float cstash[4][8];

    const int tid  = threadIdx.x;
    const int wave = tid >> 6;
    const int lane = tid & 63;
    const int row_global = blockIdx.x * 4 + wave;   // 0 .. 49151
    const int bh = row_global >> 10;
    const int q  = row_global & (LSEQ - 1);
    const int b  = bh / NH;
    const int h  = bh % NH;

    for (int i = tid; i < 5 * HDIM; i += 256)
        relk[i >> 6][i & 63] = rel_k[i];
    if (lane < 8) cstash[wave][lane] = 0.f;
    __syncthreads();

    // qrel[j] = <Q_row, rel_k[j]>   (one float per lane, wave reduce)
    const float qv = Q[((size_t)b * LSEQ + q) * DD + h * HDIM + lane];
    float qr[5];
#pragma unroll
    for (int j = 0; j < 5; j++) {
        float t = qv * relk[j][lane];
#pragma unroll
        for (int off = 32; off; off >>= 1) t += __shfl_xor(t, off);
        qr[j] = t;
    }

    float* rowp = attn + ((size_t)row_global << 10);

    // load + form logits
    float lg[16];
    float m = -1e30f;
#pragma unroll
    for (int i = 0; i < 4; i++) {
        float4 x = *(const float4*)&rowp[i*256 + lane*4];
#pragma unroll
        for (int c = 0; c < 4; c++) {
            const int k  = i*256 + lane*4 + c;
            const int dk = k - q;
            const int bkt = (dk < -2 ? -2 : (dk > 2 ? 2 : dk)) + 2;
            const float val = ((&x.x)[c] + qr[bkt]) * SCALE;
            lg[i*4 + c] = val;
            m = fmaxf(m, val);
        }
    }
#pragma unroll
    for (int off = 32; off; off >>= 1) m = fmaxf(m, __shfl_xor(m, off));

    float tot = 0.f, lft = 0.f, rgt = 0.f;
#pragma unroll
    for (int e = 0; e < 16; e++) {
        const int k = (e >> 2) * 256 + lane*4 + (e & 3);
        const float p = __expf(lg[e] - m);
        lg[e] = p;
        tot += p;
        if (k <= q - 2) lft += p;   // bucket 0 (dk <= -2)
        if (k >= q + 2) rgt += p;   // bucket 4 (dk >= +2)
    }
#pragma unroll
    for (int off = 32; off; off >>= 1) {
        tot += __shfl_xor(tot, off);
        lft += __shfl_xor(lft, off);
        rgt += __shfl_xor(rgt, off);
    }
    const float inv = 1.0f / tot;

    // normalize + store + stash diag neighborhood
#pragma unroll
    for (int i = 0; i < 4; i++) {
        float4 o;
#pragma unroll
        for (int c = 0; c < 4; c++) {
            const int k = i*256 + lane*4 + c;
            const float p = lg[i*4 + c] * inv;
            (&o.x)[c] = p;
            if (k == q - 1) cstash[wave][1] = p;
            if (k == q    ) cstash[wave][2] = p;
            if (k == q + 1) cstash[wave][3] = p;
        }
        *(float4*)&rowp[i*256 + lane*4] = o;
    }
    __syncthreads();   // uniform barrier: make cstash visible to lane 0

    if (lane == 0) {
        float* cp = coef + (size_t)row_global * 8;
        cp[0] = lft * inv;
        cp[1] = cstash[wave][1];
        cp[2] = cstash[wave][2];
        cp[3] = cstash[wave][3];
        cp[4] = rgt * inv;
    }
}

// ---------------------------------------------------------------------------
// PV GEMM + rel_v epilogue: ctx[q, h*64+c] = sum_k P[q,k] V[k,c]
//                                          + sum_j coef[q][j] rel_v[j][c]
// Tile 64(q) x 64(d), K-step 64, 256 threads, 4x4 per thread.
// P is staged k-major (Ps_t[kk][q]); V is already k-major -> both fragments
// are single ds_read_b128.
// ---------------------------------------------------------------------------
__global__ __launch_bounds__(256) void pv_kernel(
        const float* __restrict__ attn, const float* __restrict__ V,
        const float* __restrict__ coef, const float* __restrict__ rel_v,
        float* __restrict__ ctx) {
    __shared__ __align__(16) float Ps_t[64][68];
    __shared__ __align__(16) float Vs[64][68];
    __shared__ float relv[5][64];
    __shared__ float cf[64][5];

    const int tid = threadIdx.x;
    const int tx  = tid & 15;   // d-col group: cols tx*4..tx*4+3
    const int ty  = tid >> 4;   // q-row group: rows ty*4..ty*4+3
    const int bh  = blockIdx.y;
    const int m0  = blockIdx.x * 64;
    const int b   = bh / NH;
    const int h   = bh % NH;

    const float* P  = attn + ((size_t)bh << 20) + (size_t)m0 * LSEQ;
    const float* Vb = V + (size_t)b * LSEQ * DD + (size_t)h * HDIM;

    for (int i = tid; i < 5 * HDIM; i += 256)
        relv[i >> 6][i & 63] = rel_v[i];
    for (int i = tid; i < 64 * 5; i += 256) {
        const int r = i / 5, j = i % 5;
        cf[r][j] = coef[((size_t)bh * LSEQ + m0 + r) * 8 + j];
    }

    float acc[4][4];
#pragma unroll
    for (int i = 0; i < 4; i++)
#pragma unroll
        for (int j = 0; j < 4; j++) acc[i][j] = 0.f;

    for (int k0 = 0; k0 < LSEQ; k0 += 64) {
        float4 pv[4], vv[4];
#pragma unroll
        for (int t = 0; t < 4; t++) {
            const int linear = t*256 + tid;
            const int row  = linear >> 4;           // 0..63
            const int col4 = (linear & 15) * 4;     // 0..60
            pv[t] = *(const float4*)&P[(size_t)row * LSEQ + k0 + col4];
            vv[t] = *(const float4*)&Vb[(size_t)(k0 + row) * DD + col4];
        }
        __syncthreads();   // previous tile's compute done
#pragma unroll
        for (int t = 0; t < 4; t++) {
            const int linear = t*256 + tid;
            const int row  = linear >> 4;
            const int col4 = (linear & 15) * 4;
#pragma unroll
            for (int c = 0; c < 4; c++)
                Ps_t[col4 + c][row] = (&pv[t].x)[c];   // transpose: [k][q]
            *(float4*)&Vs[row][col4] = vv[t];          // [k][d]
        }
        __syncthreads();
#pragma unroll
        for (int kk = 0; kk < 64; kk++) {
            float4 pa = *(const float4*)&Ps_t[kk][ty * 4];
            float4 vw = *(const float4*)&Vs[kk][tx * 4];
#pragma unroll
            for (int i = 0; i < 4; i++)
#pragma unroll
                for (int j = 0; j < 4; j++)
                    acc[i][j] = fmaf((&pa.x)[i], (&vw.x)[j], acc[i][j]);
        }
    }

#pragma unroll
    for (int i = 0; i < 4; i++) {
        const int r = ty * 4 + i;          // local q row
        float4 o;
#pragma unroll
        for (int j = 0; j < 4; j++) {
            float v = acc[i][j];
#pragma unroll
            for (int jb = 0; jb < 5; jb++)
                v = fmaf(cf[r][jb], relv[jb][tx * 4 + j], v);
            (&o.x)[j] = v;
        }
        *(float4*)&ctx[((size_t)b * LSEQ + m0 + r) * DD + h * HDIM + tx * 4] = o;
    }
}

// ---------------------------------------------------------------------------
extern "C" void kernel_launch(void* const* d_in, const int* in_sizes, int n_in,
                              void* d_out, int out_size, void* d_ws, size_t ws_size,
                              hipStream_t stream) {
    const float* x     = (const float*)d_in[0];
    const float* Wq    = (const float*)d_in[1];
    const float* bq    = (const float*)d_in[2];
    const float* Wk    = (const float*)d_in[3];
    const float* bk    = (const float*)d_in[4];
    const float* Wv    = (const float*)d_in[5];
    const float* bv    = (const float*)d_in[6];
    const float* Wo    = (const float*)d_in[7];
    const float* bo    = (const float*)d_in[8];
    const float* rel_k = (const float*)d_in[9];
    const float* rel_v = (const float*)d_in[10];

    float* out  = (float*)d_out;                          // [B,L,D]
    float* attn = out + (size_t)NB * LSEQ * DD;           // [B,H,L,L]

    const size_t n_tok = (size_t)NB * LSEQ * DD;          // 3,145,728 floats
    float* Q    = (float*)d_ws;
    float* Kp   = Q   + n_tok;
    float* Vp   = Kp  + n_tok;
    float* coef = Vp  + n_tok;                            // 48*1024*8 floats
    float* ctx  = Q;   // alias: Q dead after softmax_kernel; ws total 37.5 MB

    // 1) Q/K/V projections
    dim3 g1(DD / 128, (NB * LSEQ) / 128, 3);              // (6, 32, 3)
    qkv_gemm<<<g1, 256, 0, stream>>>(x, Wq, bq, Q, Wk, bk, Kp, Wv, bv, Vp);

    // 2) raw logits into the attn output region
    dim3 g2(LSEQ / 128, LSEQ / 128, NB * NH);             // (8, 8, 48)
    logits_gemm<<<g2, 256, 0, stream>>>(Q, Kp, attn);

    // 3) in-place row softmax (+rel_k bucket add, *SCALE, coef emit)
    dim3 g3(NB * NH * LSEQ / 4);                          // 12288 blocks
    softmax_kernel<<<g3, 256, 0, stream>>>(Q, rel_k, attn, coef);

    // 4) PV + rel_v epilogue -> ctx  (ctx aliases Q: stream-ordered, safe)
    dim3 g4(LSEQ / 64, NB * NH);                          // (16, 48)
    pv_kernel<<<g4, 256, 0, stream>>>(attn, Vp, coef, rel_v, ctx);

    // 5) output projection
    dim3 g5(DD / 128, (NB * LSEQ) / 128, 1);              // (6, 32)
    proj_gemm<<<g5, 256, 0, stream>>>(ctx, Wo, bo, out);
}

// Round 9
// 553.984 us; speedup vs baseline: 1.3232x; 1.3232x over previous
//
#include <hip/hip_runtime.h>
#include <hip/hip_bf16.h>

#define DD    768
#define NH    12
#define HDIM  64
#define LSEQ  1024
#define NB    4
#define SCALE 27.712812921102035f   // sqrt(768): reference DIVIDES by dim**-0.5

typedef __attribute__((ext_vector_type(8))) short bf16x8;
typedef __attribute__((ext_vector_type(4))) float f32x4;

__device__ __forceinline__ ushort bf16_rne(float f) {
    uint u = __float_as_uint(f);
    return (ushort)((u + 0x7FFFu + ((u >> 16) & 1u)) >> 16);
}
__device__ __forceinline__ float bf16_tof(ushort h) {
    return __uint_as_float(((uint)h) << 16);
}
__device__ __forceinline__ void split4(const float4 v, ushort4& h, ushort4& l) {
#pragma unroll
    for (int c = 0; c < 4; c++) {
        const float f  = (&v.x)[c];
        const ushort hb = bf16_rne(f);
        (&h.x)[c] = hb;
        (&l.x)[c] = bf16_rne(f - bf16_tof(hb));
    }
}

// XCD-aware bijective block swizzle: round-robin ids -> contiguous per-XCD chunks.
// Requires nwg % 8 == 0 (true for all grids here).
__device__ __forceinline__ void swz3(int& bx, int& by, int& bz) {
    const int gx = gridDim.x, gy = gridDim.y;
    const int nwg = gx * gy * gridDim.z;
    int flat = blockIdx.x + gx * (blockIdx.y + gy * blockIdx.z);
    flat = (flat & 7) * (nwg >> 3) + (flat >> 3);
    bx = flat % gx; const int t = flat / gx; by = t % gy; bz = t / gy;
}

// ---------------------------------------------------------------------------
// Split-bf16 MFMA GEMM core: C128x128 = A[m0..+128][K] . B[n0..+128][K]^T (+bias)
// fp32 in/out; internally a = a_hi + a_lo (bf16 each), 3 MFMA terms per tile
// (hh + hl + lh; dropped lo*lo ~ 2^-16 relative). 256 threads = 4 waves (2x2),
// each wave owns a 64x64 quadrant = 4x4 fragments of 16x16x32 MFMA.
// Fragment mapping: A/B row = lane&15, k = (lane>>4)*8 + e (k-permutation
// cancels between A and B); C/D: col = lane&15, row = (lane>>4)*4 + reg.
// LDS [128][40] ushort (80 B rows = 5x16B: aligned b128 frags, ~2-way banks).
// ---------------------------------------------------------------------------
template<bool HAS_BIAS>
__device__ __forceinline__ void mfma_core(
        const float* __restrict__ A, int lda, int m0,
        const float* __restrict__ B, int ldb, int n0,
        float* __restrict__ C, int ldc,
        const float* __restrict__ bias, int K)
{
    __shared__ __align__(16) ushort Ah[128][40];
    __shared__ __align__(16) ushort Al[128][40];
    __shared__ __align__(16) ushort Bh[128][40];
    __shared__ __align__(16) ushort Bl[128][40];

    const int tid  = threadIdx.x;
    const int lane = tid & 63;
    const int wid  = tid >> 6;
    const int wr   = wid >> 1;          // wave row-half (0..1)
    const int wc   = wid & 1;           // wave col-half (0..1)
    const int lrow = lane & 15;
    const int lkg  = lane >> 4;         // 0..3

    const int sr = tid >> 3;            // 0..31 staging row per pass
    const int sc = (tid & 7) * 4;       // 0..28 staging k-col (float4)

    f32x4 acc[4][4];
#pragma unroll
    for (int i = 0; i < 4; i++)
#pragma unroll
        for (int j = 0; j < 4; j++)
#pragma unroll
            for (int e = 0; e < 4; e++) acc[i][j][e] = 0.f;

    for (int k0 = 0; k0 < K; k0 += 32) {
        float4 av[4], bv[4];
#pragma unroll
        for (int p = 0; p < 4; p++) {
            const int row = p * 32 + sr;
            av[p] = *(const float4*)&A[(size_t)(m0 + row) * lda + k0 + sc];
            bv[p] = *(const float4*)&B[(size_t)(n0 + row) * ldb + k0 + sc];
        }
        __syncthreads();   // previous step's fragment reads done
#pragma unroll
        for (int p = 0; p < 4; p++) {
            const int row = p * 32 + sr;
            ushort4 h4, l4;
            split4(av[p], h4, l4);
            *(ushort4*)&Ah[row][sc] = h4;
            *(ushort4*)&Al[row][sc] = l4;
            split4(bv[p], h4, l4);
            *(ushort4*)&Bh[row][sc] = h4;
            *(ushort4*)&Bl[row][sc] = l4;
        }
        __syncthreads();

        bf16x8 fah[4], fal[4], fbh[4], fbl[4];
#pragma unroll
        for (int t = 0; t < 4; t++) {
            fah[t] = *(const bf16x8*)&Ah[wr * 64 + t * 16 + lrow][lkg * 8];
            fal[t] = *(const bf16x8*)&Al[wr * 64 + t * 16 + lrow][lkg * 8];
            fbh[t] = *(const bf16x8*)&Bh[wc * 64 + t * 16 + lrow][lkg * 8];
            fbl[t] = *(const bf16x8*)&Bl[wc * 64 + t * 16 + lrow][lkg * 8];
        }
#pragma unroll
        for (int i = 0; i < 4; i++)
#pragma unroll
            for (int j = 0; j < 4; j++) {
                acc[i][j] = __builtin_amdgcn_mfma_f32_16x16x32_bf16(fah[i], fbh[j], acc[i][j], 0, 0, 0);
                acc[i][j] = __builtin_amdgcn_mfma_f32_16x16x32_bf16(fah[i], fbl[j], acc[i][j], 0, 0, 0);
                acc[i][j] = __builtin_amdgcn_mfma_f32_16x16x32_bf16(fal[i], fbh[j], acc[i][j], 0, 0, 0);
            }
    }

#pragma unroll
    for (int j = 0; j < 4; j++) {
        const int col = n0 + wc * 64 + j * 16 + lrow;
        const float badd = HAS_BIAS ? bias[col] : 0.f;
#pragma unroll
        for (int i = 0; i < 4; i++) {
            const int rbase = m0 + wr * 64 + i * 16 + lkg * 4;
#pragma unroll
            for (int e = 0; e < 4; e++)
                C[(size_t)(rbase + e) * ldc + col] = acc[i][j][e] + badd;
        }
    }
}

__global__ __launch_bounds__(256) void mfma_qkv(
        const float* __restrict__ x,
        const float* __restrict__ W0, const float* __restrict__ c0, float* __restrict__ O0,
        const float* __restrict__ W1, const float* __restrict__ c1, float* __restrict__ O1,
        const float* __restrict__ W2, const float* __restrict__ c2, float* __restrict__ O2) {
    int bx, by, bz; swz3(bx, by, bz);
    const float* W; const float* bias; float* C;
    if      (bz == 0) { W = W0; bias = c0; C = O0; }
    else if (bz == 1) { W = W1; bias = c1; C = O1; }
    else              { W = W2; bias = c2; C = O2; }
    mfma_core<true>(x, DD, by * 128, W, DD, bx * 128, C, DD, bias, DD);
}

__global__ __launch_bounds__(256) void mfma_proj(
        const float* __restrict__ A, const float* __restrict__ W,
        const float* __restrict__ bias, float* __restrict__ C) {
    int bx, by, bz; swz3(bx, by, bz);
    mfma_core<true>(A, DD, by * 128, W, DD, bx * 128, C, DD, bias, DD);
}

// Logits: S[q][k] = <Q_bh[q,:], K_bh[k,:]>, K-dim = 64. Raw logits to attn region.
__global__ __launch_bounds__(256) void mfma_logits(
        const float* __restrict__ Q, const float* __restrict__ Kp,
        float* __restrict__ Sout) {
    int bx, by, bz; swz3(bx, by, bz);
    const int b = bz / NH, h = bz % NH;
    const float* Ab = Q  + (size_t)b * LSEQ * DD + h * HDIM;
    const float* Bb = Kp + (size_t)b * LSEQ * DD + h * HDIM;
    float* Cb = Sout + ((size_t)bz << 20);
    mfma_core<false>(Ab, DD, by * 128, Bb, DD, bx * 128, Cb, LSEQ, nullptr, HDIM);
}

// ---------------------------------------------------------------------------
// Row softmax (in place). 4 waves/block, one wave per row. Fuses +qrel[bucket],
// *SCALE, softmax, and emits 5 rel_v bucket coefficients per row. Memory-bound.
// ---------------------------------------------------------------------------
__global__ __launch_bounds__(256) void softmax_kernel(
        const float* __restrict__ Q, const float* __restrict__ rel_k,
        float* __restrict__ attn, float* __restrict__ coef) {
    __shared__ float relk[5][64];
    __shared__ float cstash[4][8];

    const int tid  = threadIdx.x;
    const int wave = tid >> 6;
    const int lane = tid & 63;
    const int row_global = blockIdx.x * 4 + wave;
    const int bh = row_global >> 10;
    const int q  = row_global & (LSEQ - 1);
    const int b  = bh / NH;
    const int h  = bh % NH;

    for (int i = tid; i < 5 * HDIM; i += 256)
        relk[i >> 6][i & 63] = rel_k[i];
    if (lane < 8) cstash[wave][lane] = 0.f;
    __syncthreads();

    const float qv = Q[((size_t)b * LSEQ + q) * DD + h * HDIM + lane];
    float qr[5];
#pragma unroll
    for (int j = 0; j < 5; j++) {
        float t = qv * relk[j][lane];
#pragma unroll
        for (int off = 32; off; off >>= 1) t += __shfl_xor(t, off);
        qr[j] = t;
    }

    float* rowp = attn + ((size_t)row_global << 10);

    float lg[16];
    float m = -1e30f;
#pragma unroll
    for (int i = 0; i < 4; i++) {
        float4 x = *(const float4*)&rowp[i*256 + lane*4];
#pragma unroll
        for (int c = 0; c < 4; c++) {
            const int k  = i*256 + lane*4 + c;
            const int dk = k - q;
            const int bkt = (dk < -2 ? -2 : (dk > 2 ? 2 : dk)) + 2;
            const float val = ((&x.x)[c] + qr[bkt]) * SCALE;
            lg[i*4 + c] = val;
            m = fmaxf(m, val);
        }
    }
#pragma unroll
    for (int off = 32; off; off >>= 1) m = fmaxf(m, __shfl_xor(m, off));

    float tot = 0.f, lft = 0.f, rgt = 0.f;
#pragma unroll
    for (int e = 0; e < 16; e++) {
        const int k = (e >> 2) * 256 + lane*4 + (e & 3);
        const float p = __expf(lg[e] - m);
        lg[e] = p;
        tot += p;
        if (k <= q - 2) lft += p;
        if (k >= q + 2) rgt += p;
    }
#pragma unroll
    for (int off = 32; off; off >>= 1) {
        tot += __shfl_xor(tot, off);
        lft += __shfl_xor(lft, off);
        rgt += __shfl_xor(rgt, off);
    }
    const float inv = 1.0f / tot;

#pragma unroll
    for (int i = 0; i < 4; i++) {
        float4 o;
#pragma unroll
        for (int c = 0; c < 4; c++) {
            const int k = i*256 + lane*4 + c;
            const float p = lg[i*4 + c] * inv;
            (&o.x)[c] = p;
            if (k == q - 1) cstash[wave][1] = p;
            if (k == q    ) cstash[wave][2] = p;
            if (k == q + 1) cstash[wave][3] = p;
        }
        *(float4*)&rowp[i*256 + lane*4] = o;
    }
    __syncthreads();

    if (lane == 0) {
        float* cp = coef + (size_t)row_global * 8;
        cp[0] = lft * inv;
        cp[1] = cstash[wave][1];
        cp[2] = cstash[wave][2];
        cp[3] = cstash[wave][3];
        cp[4] = rgt * inv;
    }
}

// ---------------------------------------------------------------------------
// PV GEMM + rel_v epilogue (fp32 this round; MFMA-ize next if it tops profile).
// ---------------------------------------------------------------------------
__global__ __launch_bounds__(256) void pv_kernel(
        const float* __restrict__ attn, const float* __restrict__ V,
        const float* __restrict__ coef, const float* __restrict__ rel_v,
        float* __restrict__ ctx) {
    __shared__ __align__(16) float Ps_t[64][68];
    __shared__ __align__(16) float Vs[64][68];
    __shared__ float relv[5][64];
    __shared__ float cf[64][5];

    int bx, by, bz; swz3(bx, by, bz);
    const int tid = threadIdx.x;
    const int tx  = tid & 15;
    const int ty  = tid >> 4;
    const int bh  = by;
    const int m0  = bx * 64;
    const int b   = bh / NH;
    const int h   = bh % NH;

    const float* P  = attn + ((size_t)bh << 20) + (size_t)m0 * LSEQ;
    const float* Vb = V + (size_t)b * LSEQ * DD + (size_t)h * HDIM;

    for (int i = tid; i < 5 * HDIM; i += 256)
        relv[i >> 6][i & 63] = rel_v[i];
    for (int i = tid; i < 64 * 5; i += 256) {
        const int r = i / 5, j = i % 5;
        cf[r][j] = coef[((size_t)bh * LSEQ + m0 + r) * 8 + j];
    }

    float acc[4][4];
#pragma unroll
    for (int i = 0; i < 4; i++)
#pragma unroll
        for (int j = 0; j < 4; j++) acc[i][j] = 0.f;

    for (int k0 = 0; k0 < LSEQ; k0 += 64) {
        float4 pv[4], vv[4];
#pragma unroll
        for (int t = 0; t < 4; t++) {
            const int linear = t*256 + tid;
            const int row  = linear >> 4;
            const int col4 = (linear & 15) * 4;
            pv[t] = *(const float4*)&P[(size_t)row * LSEQ + k0 + col4];
            vv[t] = *(const float4*)&Vb[(size_t)(k0 + row) * DD + col4];
        }
        __syncthreads();
#pragma unroll
        for (int t = 0; t < 4; t++) {
            const int linear = t*256 + tid;
            const int row  = linear >> 4;
            const int col4 = (linear & 15) * 4;
#pragma unroll
            for (int c = 0; c < 4; c++)
                Ps_t[col4 + c][row] = (&pv[t].x)[c];
            *(float4*)&Vs[row][col4] = vv[t];
        }
        __syncthreads();
#pragma unroll
        for (int kk = 0; kk < 64; kk++) {
            float4 pa = *(const float4*)&Ps_t[kk][ty * 4];
            float4 vw = *(const float4*)&Vs[kk][tx * 4];
#pragma unroll
            for (int i = 0; i < 4; i++)
#pragma unroll
                for (int j = 0; j < 4; j++)
                    acc[i][j] = fmaf((&pa.x)[i], (&vw.x)[j], acc[i][j]);
        }
    }

#pragma unroll
    for (int i = 0; i < 4; i++) {
        const int r = ty * 4 + i;
        float4 o;
#pragma unroll
        for (int j = 0; j < 4; j++) {
            float v = acc[i][j];
#pragma unroll
            for (int jb = 0; jb < 5; jb++)
                v = fmaf(cf[r][jb], relv[jb][tx * 4 + j], v);
            (&o.x)[j] = v;
        }
        *(float4*)&ctx[((size_t)b * LSEQ + m0 + r) * DD + h * HDIM + tx * 4] = o;
    }
}

// ---------------------------------------------------------------------------
extern "C" void kernel_launch(void* const* d_in, const int* in_sizes, int n_in,
                              void* d_out, int out_size, void* d_ws, size_t ws_size,
                              hipStream_t stream) {
    const float* x     = (const float*)d_in[0];
    const float* Wq    = (const float*)d_in[1];
    const float* bq    = (const float*)d_in[2];
    const float* Wk    = (const float*)d_in[3];
    const float* bk    = (const float*)d_in[4];
    const float* Wv    = (const float*)d_in[5];
    const float* bv    = (const float*)d_in[6];
    const float* Wo    = (const float*)d_in[7];
    const float* bo    = (const float*)d_in[8];
    const float* rel_k = (const float*)d_in[9];
    const float* rel_v = (const float*)d_in[10];

    float* out  = (float*)d_out;                          // [B,L,D]
    float* attn = out + (size_t)NB * LSEQ * DD;           // [B,H,L,L]

    const size_t n_tok = (size_t)NB * LSEQ * DD;
    float* Q    = (float*)d_ws;
    float* Kp   = Q   + n_tok;
    float* Vp   = Kp  + n_tok;
    float* coef = Vp  + n_tok;
    float* ctx  = Q;   // alias: Q dead after softmax_kernel

    // 1) Q/K/V projections (split-bf16 MFMA)
    dim3 g1(DD / 128, (NB * LSEQ) / 128, 3);              // (6, 32, 3) = 576
    mfma_qkv<<<g1, 256, 0, stream>>>(x, Wq, bq, Q, Wk, bk, Kp, Wv, bv, Vp);

    // 2) raw logits into the attn output region (split-bf16 MFMA)
    dim3 g2(LSEQ / 128, LSEQ / 128, NB * NH);             // (8, 8, 48) = 3072
    mfma_logits<<<g2, 256, 0, stream>>>(Q, Kp, attn);

    // 3) in-place row softmax (+rel_k bucket add, *SCALE, coef emit)
    dim3 g3(NB * NH * LSEQ / 4);                          // 12288
    softmax_kernel<<<g3, 256, 0, stream>>>(Q, rel_k, attn, coef);

    // 4) PV + rel_v epilogue -> ctx
    dim3 g4(LSEQ / 64, NB * NH);                          // (16, 48) = 768
    pv_kernel<<<g4, 256, 0, stream>>>(attn, Vp, coef, rel_v, ctx);

    // 5) output projection (split-bf16 MFMA)
    dim3 g5(DD / 128, (NB * LSEQ) / 128, 1);              // (6, 32) = 192
    mfma_proj<<<g5, 256, 0, stream>>>(ctx, Wo, bo, out);
}

// Round 10
// 514.487 us; speedup vs baseline: 1.4248x; 1.0768x over previous
//
#include <hip/hip_runtime.h>
#include <hip/hip_bf16.h>

#define DD    768
#define NH    12
#define HDIM  64
#define LSEQ  1024
#define NB    4
#define SCALE 27.712812921102035f   // sqrt(768): reference DIVIDES by dim**-0.5

typedef __attribute__((ext_vector_type(8))) short bf16x8;
typedef __attribute__((ext_vector_type(4))) float f32x4;

__device__ __forceinline__ ushort bf16_rne(float f) {
    uint u = __float_as_uint(f);
    return (ushort)((u + 0x7FFFu + ((u >> 16) & 1u)) >> 16);
}
__device__ __forceinline__ float bf16_tof(ushort h) {
    return __uint_as_float(((uint)h) << 16);
}
__device__ __forceinline__ void split4(const float4 v, ushort4& h, ushort4& l) {
#pragma unroll
    for (int c = 0; c < 4; c++) {
        const float f  = (&v.x)[c];
        const ushort hb = bf16_rne(f);
        (&h.x)[c] = hb;
        (&l.x)[c] = bf16_rne(f - bf16_tof(hb));
    }
}

// XCD-aware bijective block swizzle (requires nwg % 8 == 0; true for all grids here).
__device__ __forceinline__ void swz3(int& bx, int& by, int& bz) {
    const int gx = gridDim.x, gy = gridDim.y;
    const int nwg = gx * gy * gridDim.z;
    int flat = blockIdx.x + gx * (blockIdx.y + gy * blockIdx.z);
    flat = (flat & 7) * (nwg >> 3) + (flat >> 3);
    bx = flat % gx; const int t = flat / gx; by = t % gy; bz = t / gy;
}

// ---------------------------------------------------------------------------
// Split-bf16 MFMA GEMM core: C128x128 = A[m0..+128][K] . B[n0..+128][K]^T (+bias)
// 3 MFMA terms (hh+hl+lh); dropped lo*lo ~2^-16 relative. 4 waves 2x2.
// Fragment maps: A/B row = lane&15, k = (lane>>4)*8+e (k-perm cancels A vs B);
// C/D col = lane&15, row = (lane>>4)*4 + reg (m89-verified).
// ---------------------------------------------------------------------------
template<bool HAS_BIAS>
__device__ __forceinline__ void mfma_core(
        const float* __restrict__ A, int lda, int m0,
        const float* __restrict__ B, int ldb, int n0,
        float* __restrict__ C, int ldc,
        const float* __restrict__ bias, int K)
{
    __shared__ __align__(16) ushort Ah[128][40];
    __shared__ __align__(16) ushort Al[128][40];
    __shared__ __align__(16) ushort Bh[128][40];
    __shared__ __align__(16) ushort Bl[128][40];

    const int tid  = threadIdx.x;
    const int lane = tid & 63;
    const int wid  = tid >> 6;
    const int wr   = wid >> 1;
    const int wc   = wid & 1;
    const int lrow = lane & 15;
    const int lkg  = lane >> 4;

    const int sr = tid >> 3;
    const int sc = (tid & 7) * 4;

    f32x4 acc[4][4];
#pragma unroll
    for (int i = 0; i < 4; i++)
#pragma unroll
        for (int j = 0; j < 4; j++)
#pragma unroll
            for (int e = 0; e < 4; e++) acc[i][j][e] = 0.f;

    for (int k0 = 0; k0 < K; k0 += 32) {
        float4 av[4], bv[4];
#pragma unroll
        for (int p = 0; p < 4; p++) {
            const int row = p * 32 + sr;
            av[p] = *(const float4*)&A[(size_t)(m0 + row) * lda + k0 + sc];
            bv[p] = *(const float4*)&B[(size_t)(n0 + row) * ldb + k0 + sc];
        }
        __syncthreads();
#pragma unroll
        for (int p = 0; p < 4; p++) {
            const int row = p * 32 + sr;
            ushort4 h4, l4;
            split4(av[p], h4, l4);
            *(ushort4*)&Ah[row][sc] = h4;
            *(ushort4*)&Al[row][sc] = l4;
            split4(bv[p], h4, l4);
            *(ushort4*)&Bh[row][sc] = h4;
            *(ushort4*)&Bl[row][sc] = l4;
        }
        __syncthreads();

        bf16x8 fah[4], fal[4], fbh[4], fbl[4];
#pragma unroll
        for (int t = 0; t < 4; t++) {
            fah[t] = *(const bf16x8*)&Ah[wr * 64 + t * 16 + lrow][lkg * 8];
            fal[t] = *(const bf16x8*)&Al[wr * 64 + t * 16 + lrow][lkg * 8];
            fbh[t] = *(const bf16x8*)&Bh[wc * 64 + t * 16 + lrow][lkg * 8];
            fbl[t] = *(const bf16x8*)&Bl[wc * 64 + t * 16 + lrow][lkg * 8];
        }
#pragma unroll
        for (int i = 0; i < 4; i++)
#pragma unroll
            for (int j = 0; j < 4; j++) {
                acc[i][j] = __builtin_amdgcn_mfma_f32_16x16x32_bf16(fah[i], fbh[j], acc[i][j], 0, 0, 0);
                acc[i][j] = __builtin_amdgcn_mfma_f32_16x16x32_bf16(fah[i], fbl[j], acc[i][j], 0, 0, 0);
                acc[i][j] = __builtin_amdgcn_mfma_f32_16x16x32_bf16(fal[i], fbh[j], acc[i][j], 0, 0, 0);
            }
    }

#pragma unroll
    for (int j = 0; j < 4; j++) {
        const int col = n0 + wc * 64 + j * 16 + lrow;
        const float badd = HAS_BIAS ? bias[col] : 0.f;
#pragma unroll
        for (int i = 0; i < 4; i++) {
            const int rbase = m0 + wr * 64 + i * 16 + lkg * 4;
#pragma unroll
            for (int e = 0; e < 4; e++)
                C[(size_t)(rbase + e) * ldc + col] = acc[i][j][e] + badd;
        }
    }
}

__global__ __launch_bounds__(256) void mfma_qkv(
        const float* __restrict__ x,
        const float* __restrict__ W0, const float* __restrict__ c0, float* __restrict__ O0,
        const float* __restrict__ W1, const float* __restrict__ c1, float* __restrict__ O1,
        const float* __restrict__ W2, const float* __restrict__ c2, float* __restrict__ O2) {
    int bx, by, bz; swz3(bx, by, bz);
    const float* W; const float* bias; float* C;
    if      (bz == 0) { W = W0; bias = c0; C = O0; }
    else if (bz == 1) { W = W1; bias = c1; C = O1; }
    else              { W = W2; bias = c2; C = O2; }
    mfma_core<true>(x, DD, by * 128, W, DD, bx * 128, C, DD, bias, DD);
}

__global__ __launch_bounds__(256) void mfma_proj(
        const float* __restrict__ A, const float* __restrict__ W,
        const float* __restrict__ bias, float* __restrict__ C) {
    int bx, by, bz; swz3(bx, by, bz);
    mfma_core<true>(A, DD, by * 128, W, DD, bx * 128, C, DD, bias, DD);
}

__global__ __launch_bounds__(256) void mfma_logits(
        const float* __restrict__ Q, const float* __restrict__ Kp,
        float* __restrict__ Sout) {
    int bx, by, bz; swz3(bx, by, bz);
    const int b = bz / NH, h = bz % NH;
    const float* Ab = Q  + (size_t)b * LSEQ * DD + h * HDIM;
    const float* Bb = Kp + (size_t)b * LSEQ * DD + h * HDIM;
    float* Cb = Sout + ((size_t)bz << 20);
    mfma_core<false>(Ab, DD, by * 128, Bb, DD, bx * 128, Cb, LSEQ, nullptr, HDIM);
}

// ---------------------------------------------------------------------------
// Row softmax (in place). 4 waves/block, one wave per row. Fuses +qrel[bucket],
// *SCALE, softmax, and emits 5 rel_v bucket coefficients per row.
// ---------------------------------------------------------------------------
__global__ __launch_bounds__(256) void softmax_kernel(
        const float* __restrict__ Q, const float* __restrict__ rel_k,
        float* __restrict__ attn, float* __restrict__ coef) {
    __shared__ float relk[5][64];
    __shared__ float cstash[4][8];

    const int tid  = threadIdx.x;
    const int wave = tid >> 6;
    const int lane = tid & 63;
    const int row_global = blockIdx.x * 4 + wave;
    const int bh = row_global >> 10;
    const int q  = row_global & (LSEQ - 1);
    const int b  = bh / NH;
    const int h  = bh % NH;

    for (int i = tid; i < 5 * HDIM; i += 256)
        relk[i >> 6][i & 63] = rel_k[i];
    if (lane < 8) cstash[wave][lane] = 0.f;
    __syncthreads();

    const float qv = Q[((size_t)b * LSEQ + q) * DD + h * HDIM + lane];
    float qr[5];
#pragma unroll
    for (int j = 0; j < 5; j++) {
        float t = qv * relk[j][lane];
#pragma unroll
        for (int off = 32; off; off >>= 1) t += __shfl_xor(t, off);
        qr[j] = t;
    }

    float* rowp = attn + ((size_t)row_global << 10);

    float lg[16];
    float m = -1e30f;
#pragma unroll
    for (int i = 0; i < 4; i++) {
        float4 x = *(const float4*)&rowp[i*256 + lane*4];
#pragma unroll
        for (int c = 0; c < 4; c++) {
            const int k  = i*256 + lane*4 + c;
            const int dk = k - q;
            const int bkt = (dk < -2 ? -2 : (dk > 2 ? 2 : dk)) + 2;
            const float val = ((&x.x)[c] + qr[bkt]) * SCALE;
            lg[i*4 + c] = val;
            m = fmaxf(m, val);
        }
    }
#pragma unroll
    for (int off = 32; off; off >>= 1) m = fmaxf(m, __shfl_xor(m, off));

    float tot = 0.f, lft = 0.f, rgt = 0.f;
#pragma unroll
    for (int e = 0; e < 16; e++) {
        const int k = (e >> 2) * 256 + lane*4 + (e & 3);
        const float p = __expf(lg[e] - m);
        lg[e] = p;
        tot += p;
        if (k <= q - 2) lft += p;
        if (k >= q + 2) rgt += p;
    }
#pragma unroll
    for (int off = 32; off; off >>= 1) {
        tot += __shfl_xor(tot, off);
        lft += __shfl_xor(lft, off);
        rgt += __shfl_xor(rgt, off);
    }
    const float inv = 1.0f / tot;

#pragma unroll
    for (int i = 0; i < 4; i++) {
        float4 o;
#pragma unroll
        for (int c = 0; c < 4; c++) {
            const int k = i*256 + lane*4 + c;
            const float p = lg[i*4 + c] * inv;
            (&o.x)[c] = p;
            if (k == q - 1) cstash[wave][1] = p;
            if (k == q    ) cstash[wave][2] = p;
            if (k == q + 1) cstash[wave][3] = p;
        }
        *(float4*)&rowp[i*256 + lane*4] = o;
    }
    __syncthreads();

    if (lane == 0) {
        float* cp = coef + (size_t)row_global * 8;
        cp[0] = lft * inv;
        cp[1] = cstash[wave][1];
        cp[2] = cstash[wave][2];
        cp[3] = cstash[wave][3];
        cp[4] = rgt * inv;
    }
}

// ---------------------------------------------------------------------------
// PV via split-bf16 MFMA + rel_v epilogue.
// ctx[q, h*64+d] = sum_k P[q,k] V[k,d] + sum_j coef[q][j] rel_v[j][d]
// Tile M=128(q) x N=64(d), K-step 32 over 1024. 4 waves 2x2: wave quadrant
// 64q x 32d = 4(m) x 2(n) fragments. P staged k-major hi/lo; V staged
// TRANSPOSED (Vt[d][k]) hi/lo so B fragments are b128 reads. ~35 KB LDS.
// ---------------------------------------------------------------------------
__global__ __launch_bounds__(256) void pv_mfma(
        const float* __restrict__ attn, const float* __restrict__ V,
        const float* __restrict__ coef, const float* __restrict__ rel_v,
        float* __restrict__ ctx) {
    __shared__ __align__(16) ushort Ph[128][40];
    __shared__ __align__(16) ushort Pl[128][40];
    __shared__ __align__(16) ushort Vth[64][40];
    __shared__ __align__(16) ushort Vtl[64][40];
    __shared__ float relv[5][64];
    __shared__ float cf[128][5];

    int bx, by, bz; swz3(bx, by, bz);
    const int tid  = threadIdx.x;
    const int lane = tid & 63;
    const int wid  = tid >> 6;
    const int wr   = wid >> 1;          // q-half (0..1)
    const int wc   = wid & 1;           // d-half (0..1)
    const int lrow = lane & 15;
    const int lkg  = lane >> 4;

    const int bh = by;
    const int m0 = bx * 128;
    const int b  = bh / NH;
    const int h  = bh % NH;

    const float* P  = attn + ((size_t)bh << 20) + (size_t)m0 * LSEQ;
    const float* Vb = V + (size_t)b * LSEQ * DD + (size_t)h * HDIM;

    for (int i = tid; i < 5 * HDIM; i += 256)
        relv[i >> 6][i & 63] = rel_v[i];
    for (int i = tid; i < 128 * 5; i += 256) {
        const int r = i / 5, j = i % 5;
        cf[r][j] = coef[((size_t)bh * LSEQ + m0 + r) * 8 + j];
    }
    // cf/relv consumed only in the epilogue (after many barriers)

    const int sr = tid >> 3;            // 0..31 P staging row
    const int sc = (tid & 7) * 4;       // 0..28 P staging k-col
    const int vr = tid >> 4;            // 0..15 V staging k-row (2 passes)
    const int vc = (tid & 15) * 4;      // 0..60 V staging d-col

    f32x4 acc[4][2];
#pragma unroll
    for (int i = 0; i < 4; i++)
#pragma unroll
        for (int j = 0; j < 2; j++)
#pragma unroll
            for (int e = 0; e < 4; e++) acc[i][j][e] = 0.f;

    for (int k0 = 0; k0 < LSEQ; k0 += 32) {
        float4 pv4[4], vv[2];
#pragma unroll
        for (int p = 0; p < 4; p++)
            pv4[p] = *(const float4*)&P[(size_t)(p * 32 + sr) * LSEQ + k0 + sc];
#pragma unroll
        for (int p = 0; p < 2; p++)
            vv[p] = *(const float4*)&Vb[(size_t)(k0 + p * 16 + vr) * DD + vc];
        __syncthreads();   // previous step's fragment reads done
#pragma unroll
        for (int p = 0; p < 4; p++) {
            ushort4 h4, l4;
            split4(pv4[p], h4, l4);
            *(ushort4*)&Ph[p * 32 + sr][sc] = h4;
            *(ushort4*)&Pl[p * 32 + sr][sc] = l4;
        }
#pragma unroll
        for (int p = 0; p < 2; p++) {
            ushort4 h4, l4;
            split4(vv[p], h4, l4);
            const int krow = p * 16 + vr;
#pragma unroll
            for (int c = 0; c < 4; c++) {
                Vth[vc + c][krow] = (&h4.x)[c];   // transpose: [d][k]
                Vtl[vc + c][krow] = (&l4.x)[c];
            }
        }
        __syncthreads();

        bf16x8 pah[4], pal[4], vbh[2], vbl[2];
#pragma unroll
        for (int t = 0; t < 4; t++) {
            pah[t] = *(const bf16x8*)&Ph[wr * 64 + t * 16 + lrow][lkg * 8];
            pal[t] = *(const bf16x8*)&Pl[wr * 64 + t * 16 + lrow][lkg * 8];
        }
#pragma unroll
        for (int t = 0; t < 2; t++) {
            vbh[t] = *(const bf16x8*)&Vth[wc * 32 + t * 16 + lrow][lkg * 8];
            vbl[t] = *(const bf16x8*)&Vtl[wc * 32 + t * 16 + lrow][lkg * 8];
        }
#pragma unroll
        for (int i = 0; i < 4; i++)
#pragma unroll
            for (int j = 0; j < 2; j++) {
                acc[i][j] = __builtin_amdgcn_mfma_f32_16x16x32_bf16(pah[i], vbh[j], acc[i][j], 0, 0, 0);
                acc[i][j] = __builtin_amdgcn_mfma_f32_16x16x32_bf16(pah[i], vbl[j], acc[i][j], 0, 0, 0);
                acc[i][j] = __builtin_amdgcn_mfma_f32_16x16x32_bf16(pal[i], vbh[j], acc[i][j], 0, 0, 0);
            }
    }

    // epilogue: + rel_v bucket reconstruction, write ctx
#pragma unroll
    for (int j = 0; j < 2; j++) {
        const int dcol = wc * 32 + j * 16 + lrow;
#pragma unroll
        for (int i = 0; i < 4; i++) {
            const int qb = wr * 64 + i * 16 + lkg * 4;
#pragma unroll
            for (int e = 0; e < 4; e++) {
                const int qloc = qb + e;
                float v = acc[i][j][e];
#pragma unroll
                for (int jb = 0; jb < 5; jb++)
                    v = fmaf(cf[qloc][jb], relv[jb][dcol], v);
                ctx[((size_t)(b * LSEQ + m0 + qloc)) * DD + h * HDIM + dcol] = v;
            }
        }
    }
}

// ---------------------------------------------------------------------------
extern "C" void kernel_launch(void* const* d_in, const int* in_sizes, int n_in,
                              void* d_out, int out_size, void* d_ws, size_t ws_size,
                              hipStream_t stream) {
    const float* x     = (const float*)d_in[0];
    const float* Wq    = (const float*)d_in[1];
    const float* bq    = (const float*)d_in[2];
    const float* Wk    = (const float*)d_in[3];
    const float* bk    = (const float*)d_in[4];
    const float* Wv    = (const float*)d_in[5];
    const float* bv    = (const float*)d_in[6];
    const float* Wo    = (const float*)d_in[7];
    const float* bo    = (const float*)d_in[8];
    const float* rel_k = (const float*)d_in[9];
    const float* rel_v = (const float*)d_in[10];

    float* out  = (float*)d_out;                          // [B,L,D]
    float* attn = out + (size_t)NB * LSEQ * DD;           // [B,H,L,L]

    const size_t n_tok = (size_t)NB * LSEQ * DD;
    float* Q    = (float*)d_ws;
    float* Kp   = Q   + n_tok;
    float* Vp   = Kp  + n_tok;
    float* coef = Vp  + n_tok;
    float* ctx  = Q;   // alias: Q dead after softmax_kernel

    // 1) Q/K/V projections (split-bf16 MFMA)
    dim3 g1(DD / 128, (NB * LSEQ) / 128, 3);              // 576 blocks
    mfma_qkv<<<g1, 256, 0, stream>>>(x, Wq, bq, Q, Wk, bk, Kp, Wv, bv, Vp);

    // 2) raw logits into the attn output region (split-bf16 MFMA)
    dim3 g2(LSEQ / 128, LSEQ / 128, NB * NH);             // 3072 blocks
    mfma_logits<<<g2, 256, 0, stream>>>(Q, Kp, attn);

    // 3) in-place row softmax (+rel_k bucket add, *SCALE, coef emit)
    dim3 g3(NB * NH * LSEQ / 4);                          // 12288 blocks
    softmax_kernel<<<g3, 256, 0, stream>>>(Q, rel_k, attn, coef);

    // 4) PV via split-bf16 MFMA + rel_v epilogue -> ctx
    dim3 g4(LSEQ / 128, NB * NH);                         // (8, 48) = 384 blocks
    pv_mfma<<<g4, 256, 0, stream>>>(attn, Vp, coef, rel_v, ctx);

    // 5) output projection (split-bf16 MFMA)
    dim3 g5(DD / 128, (NB * LSEQ) / 128, 1);              // 192 blocks
    mfma_proj<<<g5, 256, 0, stream>>>(ctx, Wo, bo, out);
}